// Round 1
// 340.000 us; speedup vs baseline: 1.1060x; 1.1060x over previous
//
#include <hip/hip_runtime.h>

typedef unsigned short u16;
typedef __bf16 bf16x8 __attribute__((ext_vector_type(8)));
typedef float f32x4 __attribute__((ext_vector_type(4)));

#define AS1 __attribute__((address_space(1)))
#define AS3 __attribute__((address_space(3)))

__device__ inline u16 f2bf(float f) {
    union { float f; unsigned u; } c; c.f = f;
    unsigned u = c.u;
    u += 0x7fffu + ((u >> 16) & 1u);   // round-to-nearest-even
    return (u16)(u >> 16);
}
__device__ inline float bf2f(u16 b) {
    union { unsigned u; float f; } c; c.u = ((unsigned)b) << 16;
    return c.f;
}

__device__ inline void async_cp16(const void* g, void* l) {
    __builtin_amdgcn_global_load_lds((const AS1 void*)g, (AS3 void*)l, 16, 0, 0);
}

// ---------------------------------------------------------------------------
// fp32 -> bf16, 8 elems/thread (x activation: 16777216 elems)
// ---------------------------------------------------------------------------
__global__ __launch_bounds__(256)
void f32_to_bf16_x8(const float* __restrict__ src, u16* __restrict__ dst) {
    int i = (blockIdx.x * 256 + threadIdx.x) * 8;
    float4 f0 = *(const float4*)(src + i);
    float4 f1 = *(const float4*)(src + i + 4);
    union { u16 h[8]; uint4 v; } o;
    o.h[0] = f2bf(f0.x); o.h[1] = f2bf(f0.y);
    o.h[2] = f2bf(f0.z); o.h[3] = f2bf(f0.w);
    o.h[4] = f2bf(f1.x); o.h[5] = f2bf(f1.y);
    o.h[6] = f2bf(f1.z); o.h[7] = f2bf(f1.w);
    *(uint4*)(dst + i) = o.v;
}

// ---------------------------------------------------------------------------
// All four weight matrices in ONE launch (same as previous round).
// ---------------------------------------------------------------------------
__global__ __launch_bounds__(256)
void conv_weights(const float* __restrict__ wq, const float* __restrict__ wk,
                  const float* __restrict__ wv, const float* __restrict__ wo,
                  u16* __restrict__ wqkv, u16* __restrict__ wo_bf) {
    int i = (blockIdx.x * 256 + threadIdx.x) * 4;
    const float* src;
    u16* dst;
    if (i < 4194304)       { src = wq + i;           dst = wqkv + i; }
    else if (i < 5242880)  { src = wk + (i-4194304); dst = wqkv + i; }
    else if (i < 6291456)  { src = wv + (i-5242880); dst = wqkv + i; }
    else                   { src = wo + (i-6291456); dst = wo_bf + (i-6291456); }
    float4 f = *(const float4*)src;
    union { u16 h[4]; uint2 v; } o;
    o.h[0] = f2bf(f.x); o.h[1] = f2bf(f.y);
    o.h[2] = f2bf(f.z); o.h[3] = f2bf(f.w);
    *(uint2*)dst = o.v;
}

// ---------------------------------------------------------------------------
// 256x256x(BK=64) 8-phase bf16 GEMM, C = A * B^T (row-major, K contiguous).
// 512 threads = 8 waves (2M x 4N), per-wave output 128x64, acc[8][4] f32x4.
// LDS 128 KiB: [2 buf][A 256x64 | B 256x64] u16, rows of 128 B, XOR-chunk
// swizzle LDS[r][p] = global[r][p ^ (r&7)] (16-B chunks) -- conflict-free
// ds_read_b128 frags, staged via global_load_lds w=16 with pre-swizzled
// global source (wave-uniform LDS dest + lane*16).
//
// Schedule (per half-iteration on K-tile u, buf BO = (u&1)*64KiB):
//   P1: ds_read bg[4][2] + af mi0-3 (16); stage (u+1).A1; lgkm(8); bar;
//       lgkm(0); prio1; 16 MFMA (mi0-1); prio0; bar
//   P2: ds_read af mi4-5 (4); stage (u+2).B0; bar; lgkm(0); MFMA mi2-3; bar
//   P3: ds_read af mi6-7 (4); stage (u+2).B1; bar; lgkm(0); MFMA mi4-5; bar
//   P4: stage (u+2).A0; bar; MFMA mi6-7; vmcnt(6); bar
// Invariants (checked): every LDS region's last ds_read is issued >=1 phase
// before its overwriting stage (the intervening lgkmcnt(0)+barrier makes the
// overwrite race-free), and every staged half has >=3 phases of slack before
// the vmcnt(6) that covers its first read. vmcnt never drains to 0 in-loop.
// Requires: M,N %256==0, K %128==0.
// ---------------------------------------------------------------------------
template <bool BF16_OUT>
__global__ __launch_bounds__(512, 2)
void gemm_bt8(const u16* __restrict__ A, const u16* __restrict__ B,
              void* __restrict__ Cout, int N, int K) {
    __shared__ __align__(16) u16 lds[65536];   // 128 KiB
    char* ldsc = (char*)lds;

    const int tid  = threadIdx.x;
    const int w    = tid >> 6;
    const int lane = tid & 63;
    const int row0 = blockIdx.x * 256;
    const int col0 = blockIdx.y * 256;
    const int wm = w >> 2, wn = w & 3;
    const int lm = lane & 15, quad = lane >> 4;

    const int NT  = K / 64;     // K-tiles
    const int NIT = K / 128;    // main-loop iterations (2 tiles each)
    const int K64 = K * 64, K128 = K * 128;

    // staging: lane l covers row (8w + (l>>3)) within a 64-row inst-round,
    // LDS chunk position l&7 holds global chunk (l&7)^(l>>3)  (swizzle)
    const int sr  = lane >> 3;
    const int stC = ((lane & 7) ^ sr) * 8;
    const u16* pA = A + (size_t)(row0 + w * 8 + sr) * K + stC;
    const u16* pB = B + (size_t)(col0 + w * 8 + sr) * K + stC;
    const int stagoff = w * 1024;

    // fragment read bases (byte offsets); row&7 == lm&7 for all frag rows
    const int cx0   = (quad ^ (lm & 7)) * 16;
    const int cx1   = cx0 ^ 64;
    const int aBase = (wm * 128 + lm) * 128;
    const int bBase = 32768 + (wn * 64 + lm) * 128;

    f32x4 acc[8][4];
#pragma unroll
    for (int i = 0; i < 8; i++)
#pragma unroll
        for (int j = 0; j < 4; j++) acc[i][j] = (f32x4){0.f, 0.f, 0.f, 0.f};

    auto stA = [&](int v, int h) {   // stage A half h (rows h*128..+128) of tile v
        int kb = (v < NT ? v : NT - 1) * 64;           // clamp: tail re-stage
        const u16* g = pA + h * K128 + kb;
        char* d = ldsc + ((v & 1) << 16) + h * 16384 + stagoff;
        async_cp16(g, d);
        async_cp16(g + K64, d + 8192);
    };
    auto stB = [&](int v, int h) {
        int kb = (v < NT ? v : NT - 1) * 64;
        const u16* g = pB + h * K128 + kb;
        char* d = ldsc + ((v & 1) << 16) + 32768 + h * 16384 + stagoff;
        async_cp16(g, d);
        async_cp16(g + K64, d + 8192);
    };

    // prologue: t0 complete + t1.{B0,B1,A0}  (7 half-tiles, 14 loads)
    stB(0, 0); stB(0, 1); stA(0, 0); stA(0, 1);
    stB(1, 0); stB(1, 1); stA(1, 0);
    asm volatile("s_waitcnt vmcnt(6)" ::: "memory");   // t0 landed
    __builtin_amdgcn_s_barrier();

    bf16x8 bg[4][2], afX[2][2], afY[2][2];

#define LDR(off) (*(const bf16x8*)(ldsc + (off)))

#define PHASE_TAIL(MI0, AF)                                                   \
    __builtin_amdgcn_s_barrier();                                             \
    asm volatile("s_waitcnt lgkmcnt(0)" ::: "memory");                        \
    __builtin_amdgcn_sched_barrier(0);                                        \
    __builtin_amdgcn_s_setprio(1);                                            \
    _Pragma("unroll")                                                         \
    for (int s = 0; s < 2; s++)                                               \
        _Pragma("unroll")                                                     \
        for (int j = 0; j < 2; j++)                                           \
            _Pragma("unroll")                                                 \
            for (int ni = 0; ni < 4; ni++)                                    \
                acc[(MI0) + j][ni] = __builtin_amdgcn_mfma_f32_16x16x32_bf16( \
                    AF[j][s], bg[ni][s], acc[(MI0) + j][ni], 0, 0, 0);        \
    __builtin_amdgcn_s_setprio(0);

#define HALF_ITER(u, BO)                                                      \
    {                                                                         \
        /* P1 */                                                              \
        _Pragma("unroll")                                                     \
        for (int ni = 0; ni < 4; ni++) {                                      \
            bg[ni][0] = LDR((BO) + bBase + ni * 2048 + cx0);                  \
            bg[ni][1] = LDR((BO) + bBase + ni * 2048 + cx1);                  \
        }                                                                     \
        _Pragma("unroll")                                                     \
        for (int j = 0; j < 2; j++) {                                         \
            afX[j][0] = LDR((BO) + aBase + j * 2048 + cx0);                   \
            afX[j][1] = LDR((BO) + aBase + j * 2048 + cx1);                   \
            afY[j][0] = LDR((BO) + aBase + (2 + j) * 2048 + cx0);             \
            afY[j][1] = LDR((BO) + aBase + (2 + j) * 2048 + cx1);             \
        }                                                                     \
        stA((u) + 1, 1);                                                      \
        asm volatile("s_waitcnt lgkmcnt(8)" ::: "memory");                    \
        PHASE_TAIL(0, afX)                                                    \
        __builtin_amdgcn_s_barrier();                                         \
        /* P2 */                                                              \
        _Pragma("unroll")                                                     \
        for (int j = 0; j < 2; j++) {                                         \
            afX[j][0] = LDR((BO) + aBase + (4 + j) * 2048 + cx0);             \
            afX[j][1] = LDR((BO) + aBase + (4 + j) * 2048 + cx1);             \
        }                                                                     \
        stB((u) + 2, 0);                                                      \
        PHASE_TAIL(2, afY)                                                    \
        __builtin_amdgcn_s_barrier();                                         \
        /* P3 */                                                              \
        _Pragma("unroll")                                                     \
        for (int j = 0; j < 2; j++) {                                         \
            afY[j][0] = LDR((BO) + aBase + (6 + j) * 2048 + cx0);             \
            afY[j][1] = LDR((BO) + aBase + (6 + j) * 2048 + cx1);             \
        }                                                                     \
        stB((u) + 2, 1);                                                      \
        PHASE_TAIL(4, afX)                                                    \
        __builtin_amdgcn_s_barrier();                                         \
        /* P4 */                                                              \
        stA((u) + 2, 0);                                                      \
        PHASE_TAIL(6, afY)                                                    \
        asm volatile("s_waitcnt vmcnt(6)" ::: "memory");                      \
        __builtin_amdgcn_s_barrier();                                         \
    }

    for (int it = 0; it < NIT; ++it) {
        const int t = 2 * it;
        HALF_ITER(t, 0)
        HALF_ITER(t + 1, 65536)
    }

#undef HALF_ITER
#undef PHASE_TAIL
#undef LDR

    // epilogue: C/D layout col = lane&15, row = quad*4 + reg
    const int rbase = row0 + wm * 128 + quad * 4;
    const int cbase = col0 + wn * 64 + lm;
    if (BF16_OUT) {
        u16* C = (u16*)Cout;
#pragma unroll
        for (int mi = 0; mi < 8; mi++)
#pragma unroll
            for (int r = 0; r < 4; r++) {
                size_t ro = (size_t)(rbase + mi * 16 + r) * N;
#pragma unroll
                for (int ni = 0; ni < 4; ni++)
                    C[ro + cbase + ni * 16] = f2bf(acc[mi][ni][r]);
            }
    } else {
        float* C = (float*)Cout;
#pragma unroll
        for (int mi = 0; mi < 8; mi++)
#pragma unroll
            for (int r = 0; r < 4; r++) {
                size_t ro = (size_t)(rbase + mi * 16 + r) * N;
#pragma unroll
                for (int ni = 0; ni < 4; ni++)
                    C[ro + cbase + ni * 16] = acc[mi][ni][r];
            }
    }
}

// ---------------------------------------------------------------------------
// Per-token attention. qkv row: [q(2048) | k(512) | v(512)] bf16.
// RoPE dropped (same-position q/k rotation cancels in the dot);
// 4x head repeat collapsed (softmax over 8 distinct kv-heads).
// ---------------------------------------------------------------------------
__global__ __launch_bounds__(256)
void attn_tok(const u16* __restrict__ qkv, u16* __restrict__ out) {
    __shared__ float kvf[1024];   // k (512 floats) then v (512 floats)
    const int tok = blockIdx.x;
    const int t = threadIdx.x;
    const u16* qrow = qkv + (size_t)tok * 3072;

    {   // stage k|v (contiguous 1024 bf16) into LDS as fp32
        uint2 w = *(const uint2*)(qrow + 2048 + t * 4);
        kvf[t * 4 + 0] = bf2f((u16)(w.x & 0xffff));
        kvf[t * 4 + 1] = bf2f((u16)(w.x >> 16));
        kvf[t * 4 + 2] = bf2f((u16)(w.y & 0xffff));
        kvf[t * 4 + 3] = bf2f((u16)(w.y >> 16));
    }
    __syncthreads();

    const int h = t >> 3, j = t & 7;
    float qf[8];
    {
        uint4 w = *(const uint4*)(qrow + h * 64 + j * 8);
        unsigned ws4[4] = {w.x, w.y, w.z, w.w};
#pragma unroll
        for (int i = 0; i < 4; i++) {
            qf[2 * i]     = bf2f((u16)(ws4[i] & 0xffff));
            qf[2 * i + 1] = bf2f((u16)(ws4[i] >> 16));
        }
    }

    float s[8];
#pragma unroll
    for (int g = 0; g < 8; g++) {
        const float* kk = kvf + g * 64 + j * 8;
        float a = 0.f;
#pragma unroll
        for (int d = 0; d < 8; d++) a += qf[d] * kk[d];
        s[g] = a;
    }
#pragma unroll
    for (int g = 0; g < 8; g++) {   // reduce across the head's 8 lanes
        s[g] += __shfl_xor(s[g], 1);
        s[g] += __shfl_xor(s[g], 2);
        s[g] += __shfl_xor(s[g], 4);
    }
    float m = -1e30f;
#pragma unroll
    for (int g = 0; g < 8; g++) { s[g] *= 0.125f; m = fmaxf(m, s[g]); }
    float p[8], l = 0.f;
#pragma unroll
    for (int g = 0; g < 8; g++) { p[g] = __expf(s[g] - m); l += p[g]; }
    float rl = 1.f / l;

    float o[8] = {0, 0, 0, 0, 0, 0, 0, 0};
#pragma unroll
    for (int g = 0; g < 8; g++) {
        float w = p[g] * rl;
        const float* vv = kvf + 512 + g * 64 + j * 8;
#pragma unroll
        for (int d = 0; d < 8; d++) o[d] += w * vv[d];
    }

    unsigned po[4];
#pragma unroll
    for (int i = 0; i < 4; i++)
        po[i] = (unsigned)f2bf(o[2 * i]) | ((unsigned)f2bf(o[2 * i + 1]) << 16);
    uint4 wo_; wo_.x = po[0]; wo_.y = po[1]; wo_.z = po[2]; wo_.w = po[3];
    *(uint4*)(out + (size_t)tok * 2048 + h * 64 + j * 8) = wo_;
}

// ---------------------------------------------------------------------------
// B=4, S=2048, DIM=2048, H=32, KVH=8, HD=64. Tokens M = 8192.
// Workspace (u16 elems): x_bf 16777216 | wqkv 6291456 | wo_bf 4194304
//                        | qkv 25165824 | attn 16777216  (138.4 MB)
// ---------------------------------------------------------------------------
extern "C" void kernel_launch(void* const* d_in, const int* in_sizes, int n_in,
                              void* d_out, int out_size, void* d_ws, size_t ws_size,
                              hipStream_t stream) {
    const float* x  = (const float*)d_in[0];
    const float* wq = (const float*)d_in[1];
    const float* wk = (const float*)d_in[2];
    const float* wv = (const float*)d_in[3];
    const float* wo = (const float*)d_in[4];
    // d_in[5]/d_in[6] (freqs_cos/sin) unused: RoPE cancels in same-position dots.

    u16* x_bf  = (u16*)d_ws;
    u16* wqkv  = x_bf  + 16777216;
    u16* wo_bf = wqkv  + 6291456;
    u16* qkv   = wo_bf + 4194304;    // 8192 x 3072
    u16* attn  = qkv   + 25165824;   // 8192 x 2048

    f32_to_bf16_x8<<<8192, dim3(256), 0, stream>>>(x, x_bf);
    conv_weights<<<10240, dim3(256), 0, stream>>>(wq, wk, wv, wo, wqkv, wo_bf);

    // fused QKV projection: [8192 x 2048] x [3072 x 2048]^T -> [8192 x 3072]
    gemm_bt8<true><<<dim3(32, 12), dim3(512), 0, stream>>>(x_bf, wqkv, qkv, 3072, 2048);

    attn_tok<<<8192, dim3(256), 0, stream>>>(qkv, attn);

    // output projection: [8192 x 2048] x [2048 x 2048]^T -> fp32 d_out
    gemm_bt8<false><<<dim3(32, 8), dim3(512), 0, stream>>>(attn, wo_bf, (float*)d_out,
                                                           2048, 2048);
}

// Round 2
// 328.866 us; speedup vs baseline: 1.1434x; 1.0339x over previous
//
#include <hip/hip_runtime.h>

typedef unsigned short u16;
typedef __bf16 bf16x8 __attribute__((ext_vector_type(8)));
typedef float f32x4 __attribute__((ext_vector_type(4)));

#define AS1 __attribute__((address_space(1)))
#define AS3 __attribute__((address_space(3)))

__device__ inline u16 f2bf(float f) {
    union { float f; unsigned u; } c; c.f = f;
    unsigned u = c.u;
    u += 0x7fffu + ((u >> 16) & 1u);   // round-to-nearest-even
    return (u16)(u >> 16);
}
__device__ inline float bf2f(u16 b) {
    union { unsigned u; float f; } c; c.u = ((unsigned)b) << 16;
    return c.f;
}

__device__ inline void async_cp16(const void* g, void* l) {
    __builtin_amdgcn_global_load_lds((const AS1 void*)g, (AS3 void*)l, 16, 0, 0);
}

// ---------------------------------------------------------------------------
// Fused input conversions in ONE launch:
//   blocks [0, 8192):      x fp32 -> bf16, 8 elems/thread (16777216 elems)
//   blocks [8192, 18432):  wq|wk|wv -> wqkv, wo -> wo_bf, 4 elems/thread
// ---------------------------------------------------------------------------
__global__ __launch_bounds__(256)
void conv_all(const float* __restrict__ x,
              const float* __restrict__ wq, const float* __restrict__ wk,
              const float* __restrict__ wv, const float* __restrict__ wo,
              u16* __restrict__ x_bf, u16* __restrict__ wqkv,
              u16* __restrict__ wo_bf) {
    int b = blockIdx.x;
    if (b < 8192) {
        int i = (b * 256 + threadIdx.x) * 8;
        float4 f0 = *(const float4*)(x + i);
        float4 f1 = *(const float4*)(x + i + 4);
        union { u16 h[8]; uint4 v; } o;
        o.h[0] = f2bf(f0.x); o.h[1] = f2bf(f0.y);
        o.h[2] = f2bf(f0.z); o.h[3] = f2bf(f0.w);
        o.h[4] = f2bf(f1.x); o.h[5] = f2bf(f1.y);
        o.h[6] = f2bf(f1.z); o.h[7] = f2bf(f1.w);
        *(uint4*)(x_bf + i) = o.v;
    } else {
        int i = ((b - 8192) * 256 + threadIdx.x) * 4;
        const float* src;
        u16* dst;
        if (i < 4194304)       { src = wq + i;           dst = wqkv + i; }
        else if (i < 5242880)  { src = wk + (i-4194304); dst = wqkv + i; }
        else if (i < 6291456)  { src = wv + (i-5242880); dst = wqkv + i; }
        else                   { src = wo + (i-6291456); dst = wo_bf + (i-6291456); }
        float4 f = *(const float4*)src;
        union { u16 h[4]; uint2 v; } o;
        o.h[0] = f2bf(f.x); o.h[1] = f2bf(f.y);
        o.h[2] = f2bf(f.z); o.h[3] = f2bf(f.w);
        *(uint2*)dst = o.v;
    }
}

// ---------------------------------------------------------------------------
// 256 x (NI*64) x (BK=64) 8-phase bf16 GEMM, C = A * B^T (row-major, K contig).
// 512 threads = 8 waves (2M x 4N), per-wave output 128 x (NI*16), acc[8][NI].
// NI=4: the round-1 proven 256x256 schedule (identical ledger, vmcnt(6)).
// NI=3: 256x192 tile -> QKV grid 32x16 = 512 blocks = 2 EXACT machine rounds
//       (fixes the 384-block 1.5-round tail that cost 25%), vmcnt(5).
//
// LDS per buffer: A 256x64 u16 (32 KiB) | B NI*64 x 64 u16 (NI*8 KiB); 2 bufs.
// XOR-chunk swizzle LDS[r][p] = global[r][p ^ (r&7)] (16-B chunks); staged via
// global_load_lds w=16 with pre-swizzled global source (wave-uniform LDS dest).
//
// Staging units = one async_cp16/thread = 64 rows. A-units 0..3, B-units 0..NI-1.
// Region lifetimes per K-tile: A0,A2 last read in P1; A1,A3 in P3; B in P1.
// Schedule per K-tile u (buf = u&1):
//   P1: ds_read bg[NI][2] + af mi0-3; stage A2,A3(u+1) [other buf];
//       lgkm(8); bar; lgkm(0); prio1; MFMA mi0-1; prio0; bar
//   P2: ds_read af mi4-5; stage B0,B1(u+2); bar; lgkm(0); MFMA mi2-3; bar
//   P3: ds_read af mi6-7; stage B2,[B3|A0](u+2); bar; lgkm(0); MFMA mi4-5; bar
//   P4: stage [A0,A1|A1](u+2); bar; MFMA mi6-7; vmcnt(NI+2); bar
// vmcnt(NI+2) keeps exactly tile (u+2)'s units in flight -> (u+1) fully landed
// before its P1; same-parity stages only touch regions consumed >=1 barrier ago.
// Requires: M %256==0, N %(NI*64)==0, K %128==0.
// ---------------------------------------------------------------------------
template <int NI, bool BF16_OUT>
__global__ __launch_bounds__(512, 2)
void gemm_bt8(const u16* __restrict__ A, const u16* __restrict__ B,
              void* __restrict__ Cout, int N, int K) {
    constexpr int SZ = 32768 + NI * 8192;       // bytes per LDS buffer
    __shared__ __align__(16) char ldsc[2 * SZ];

    const int tid  = threadIdx.x;
    const int w    = tid >> 6;
    const int lane = tid & 63;
    const int row0 = blockIdx.x * 256;
    const int col0 = blockIdx.y * (NI * 64);
    const int wm = w >> 2, wn = w & 3;
    const int lm = lane & 15, quad = lane >> 4;

    const int NT  = K / 64;     // K-tiles
    const int NIT = K / 128;    // main-loop iterations (2 tiles each)
    const int K64 = K * 64;

    // staging: lane l covers row (8w + (l>>3)) within a 64-row unit,
    // LDS chunk position l&7 holds global chunk (l&7)^(l>>3)  (swizzle)
    const int sr  = lane >> 3;
    const int stC = ((lane & 7) ^ sr) * 8;
    const u16* pA = A + (size_t)(row0 + w * 8 + sr) * K + stC;
    const u16* pB = B + (size_t)(col0 + w * 8 + sr) * K + stC;
    const int stagoff = w * 1024;

    // fragment read bases (byte offsets); frag row&7 == lm&7 (row blocks %8==0)
    const int cx0   = (quad ^ (lm & 7)) * 16;
    const int cx1   = cx0 ^ 64;
    const int aBase = (wm * 128 + lm) * 128;
    const int bBase = 32768 + (wn * (NI * 16) + lm) * 128;

    f32x4 acc[8][NI];
#pragma unroll
    for (int i = 0; i < 8; i++)
#pragma unroll
        for (int j = 0; j < NI; j++) acc[i][j] = (f32x4){0.f, 0.f, 0.f, 0.f};

    auto stage = [&](const u16* base, int v, int unit, int regionOff) {
        int kb = (v < NT ? v : NT - 1) * 64;    // clamp: tail re-stage (dup data)
        async_cp16(base + (size_t)unit * K64 + kb,
                   ldsc + (v & 1) * SZ + regionOff + unit * 8192 + stagoff);
    };
#define ST_A(v, u) stage(pA, (v), (u), 0)
#define ST_B(v, u) stage(pB, (v), (u), 32768)

    // prologue: t0 complete (4+NI units) + t1 {B*, A0, A1} (NI+2 units)
#pragma unroll
    for (int u = 0; u < 4; u++) ST_A(0, u);
#pragma unroll
    for (int u = 0; u < NI; u++) ST_B(0, u);
#pragma unroll
    for (int u = 0; u < NI; u++) ST_B(1, u);
    ST_A(1, 0); ST_A(1, 1);
    if constexpr (NI == 4) asm volatile("s_waitcnt vmcnt(6)" ::: "memory");
    else                   asm volatile("s_waitcnt vmcnt(5)" ::: "memory");
    __builtin_amdgcn_s_barrier();

    bf16x8 bg[NI][2], afX[2][2], afY[2][2];

#define LDR(off) (*(const bf16x8*)(ldsc + (off)))

#define PHASE_TAIL(MI0, AF)                                                   \
    __builtin_amdgcn_s_barrier();                                             \
    asm volatile("s_waitcnt lgkmcnt(0)" ::: "memory");                        \
    __builtin_amdgcn_sched_barrier(0);                                        \
    __builtin_amdgcn_s_setprio(1);                                            \
    _Pragma("unroll")                                                         \
    for (int s = 0; s < 2; s++)                                               \
        _Pragma("unroll")                                                     \
        for (int j = 0; j < 2; j++)                                           \
            _Pragma("unroll")                                                 \
            for (int ni = 0; ni < NI; ni++)                                   \
                acc[(MI0) + j][ni] = __builtin_amdgcn_mfma_f32_16x16x32_bf16( \
                    AF[j][s], bg[ni][s], acc[(MI0) + j][ni], 0, 0, 0);        \
    __builtin_amdgcn_s_setprio(0);

#define HALF_ITER(u, BO)                                                      \
    {                                                                         \
        /* P1 */                                                              \
        _Pragma("unroll")                                                     \
        for (int ni = 0; ni < NI; ni++) {                                     \
            bg[ni][0] = LDR((BO) + bBase + ni * 2048 + cx0);                  \
            bg[ni][1] = LDR((BO) + bBase + ni * 2048 + cx1);                  \
        }                                                                     \
        _Pragma("unroll")                                                     \
        for (int j = 0; j < 2; j++) {                                         \
            afX[j][0] = LDR((BO) + aBase + j * 2048 + cx0);                   \
            afX[j][1] = LDR((BO) + aBase + j * 2048 + cx1);                   \
            afY[j][0] = LDR((BO) + aBase + (2 + j) * 2048 + cx0);             \
            afY[j][1] = LDR((BO) + aBase + (2 + j) * 2048 + cx1);             \
        }                                                                     \
        ST_A((u) + 1, 2); ST_A((u) + 1, 3);                                   \
        asm volatile("s_waitcnt lgkmcnt(8)" ::: "memory");                    \
        PHASE_TAIL(0, afX)                                                    \
        __builtin_amdgcn_s_barrier();                                         \
        /* P2 */                                                              \
        _Pragma("unroll")                                                     \
        for (int j = 0; j < 2; j++) {                                         \
            afX[j][0] = LDR((BO) + aBase + (4 + j) * 2048 + cx0);             \
            afX[j][1] = LDR((BO) + aBase + (4 + j) * 2048 + cx1);             \
        }                                                                     \
        ST_B((u) + 2, 0); ST_B((u) + 2, 1);                                   \
        PHASE_TAIL(2, afY)                                                    \
        __builtin_amdgcn_s_barrier();                                         \
        /* P3 */                                                              \
        _Pragma("unroll")                                                     \
        for (int j = 0; j < 2; j++) {                                         \
            afY[j][0] = LDR((BO) + aBase + (6 + j) * 2048 + cx0);             \
            afY[j][1] = LDR((BO) + aBase + (6 + j) * 2048 + cx1);             \
        }                                                                     \
        ST_B((u) + 2, 2);                                                     \
        if constexpr (NI == 4) { ST_B((u) + 2, 3); }                          \
        else                   { ST_A((u) + 2, 0); }                          \
        PHASE_TAIL(4, afX)                                                    \
        __builtin_amdgcn_s_barrier();                                         \
        /* P4 */                                                              \
        if constexpr (NI == 4) { ST_A((u) + 2, 0); ST_A((u) + 2, 1); }        \
        else                   { ST_A((u) + 2, 1); }                          \
        PHASE_TAIL(6, afY)                                                    \
        if constexpr (NI == 4) asm volatile("s_waitcnt vmcnt(6)" ::: "memory");\
        else                   asm volatile("s_waitcnt vmcnt(5)" ::: "memory");\
        __builtin_amdgcn_s_barrier();                                         \
    }

    for (int it = 0; it < NIT; ++it) {
        const int t = 2 * it;
        HALF_ITER(t, 0)
        HALF_ITER(t + 1, SZ)
    }

#undef HALF_ITER
#undef PHASE_TAIL
#undef LDR
#undef ST_A
#undef ST_B

    // epilogue: C/D layout col = lane&15, row = quad*4 + reg
    const int rbase = row0 + wm * 128 + quad * 4;
    const int cbase = col0 + wn * (NI * 16) + lm;
    if (BF16_OUT) {
        u16* C = (u16*)Cout;
#pragma unroll
        for (int mi = 0; mi < 8; mi++)
#pragma unroll
            for (int r = 0; r < 4; r++) {
                size_t ro = (size_t)(rbase + mi * 16 + r) * N;
#pragma unroll
                for (int ni = 0; ni < NI; ni++)
                    C[ro + cbase + ni * 16] = f2bf(acc[mi][ni][r]);
            }
    } else {
        float* C = (float*)Cout;
#pragma unroll
        for (int mi = 0; mi < 8; mi++)
#pragma unroll
            for (int r = 0; r < 4; r++) {
                size_t ro = (size_t)(rbase + mi * 16 + r) * N;
#pragma unroll
                for (int ni = 0; ni < NI; ni++)
                    C[ro + cbase + ni * 16] = acc[mi][ni][r];
            }
    }
}

// ---------------------------------------------------------------------------
// Per-token attention. qkv row: [q(2048) | k(512) | v(512)] bf16.
// RoPE dropped (same-position q/k rotation cancels in the dot);
// 4x head repeat collapsed (softmax over 8 distinct kv-heads).
// ---------------------------------------------------------------------------
__global__ __launch_bounds__(256)
void attn_tok(const u16* __restrict__ qkv, u16* __restrict__ out) {
    __shared__ float kvf[1024];   // k (512 floats) then v (512 floats)
    const int tok = blockIdx.x;
    const int t = threadIdx.x;
    const u16* qrow = qkv + (size_t)tok * 3072;

    {   // stage k|v (contiguous 1024 bf16) into LDS as fp32
        uint2 w = *(const uint2*)(qrow + 2048 + t * 4);
        kvf[t * 4 + 0] = bf2f((u16)(w.x & 0xffff));
        kvf[t * 4 + 1] = bf2f((u16)(w.x >> 16));
        kvf[t * 4 + 2] = bf2f((u16)(w.y & 0xffff));
        kvf[t * 4 + 3] = bf2f((u16)(w.y >> 16));
    }
    __syncthreads();

    const int h = t >> 3, j = t & 7;
    float qf[8];
    {
        uint4 w = *(const uint4*)(qrow + h * 64 + j * 8);
        unsigned ws4[4] = {w.x, w.y, w.z, w.w};
#pragma unroll
        for (int i = 0; i < 4; i++) {
            qf[2 * i]     = bf2f((u16)(ws4[i] & 0xffff));
            qf[2 * i + 1] = bf2f((u16)(ws4[i] >> 16));
        }
    }

    float s[8];
#pragma unroll
    for (int g = 0; g < 8; g++) {
        const float* kk = kvf + g * 64 + j * 8;
        float a = 0.f;
#pragma unroll
        for (int d = 0; d < 8; d++) a += qf[d] * kk[d];
        s[g] = a;
    }
#pragma unroll
    for (int g = 0; g < 8; g++) {   // reduce across the head's 8 lanes
        s[g] += __shfl_xor(s[g], 1);
        s[g] += __shfl_xor(s[g], 2);
        s[g] += __shfl_xor(s[g], 4);
    }
    float m = -1e30f;
#pragma unroll
    for (int g = 0; g < 8; g++) { s[g] *= 0.125f; m = fmaxf(m, s[g]); }
    float p[8], l = 0.f;
#pragma unroll
    for (int g = 0; g < 8; g++) { p[g] = __expf(s[g] - m); l += p[g]; }
    float rl = 1.f / l;

    float o[8] = {0, 0, 0, 0, 0, 0, 0, 0};
#pragma unroll
    for (int g = 0; g < 8; g++) {
        float w = p[g] * rl;
        const float* vv = kvf + 512 + g * 64 + j * 8;
#pragma unroll
        for (int d = 0; d < 8; d++) o[d] += w * vv[d];
    }

    unsigned po[4];
#pragma unroll
    for (int i = 0; i < 4; i++)
        po[i] = (unsigned)f2bf(o[2 * i]) | ((unsigned)f2bf(o[2 * i + 1]) << 16);
    uint4 wo_; wo_.x = po[0]; wo_.y = po[1]; wo_.z = po[2]; wo_.w = po[3];
    *(uint4*)(out + (size_t)tok * 2048 + h * 64 + j * 8) = wo_;
}

// ---------------------------------------------------------------------------
// B=4, S=2048, DIM=2048, H=32, KVH=8, HD=64. Tokens M = 8192.
// Workspace (u16 elems): x_bf 16777216 | wqkv 6291456 | wo_bf 4194304
//                        | qkv 25165824 | attn 16777216  (138.4 MB)
// ---------------------------------------------------------------------------
extern "C" void kernel_launch(void* const* d_in, const int* in_sizes, int n_in,
                              void* d_out, int out_size, void* d_ws, size_t ws_size,
                              hipStream_t stream) {
    const float* x  = (const float*)d_in[0];
    const float* wq = (const float*)d_in[1];
    const float* wk = (const float*)d_in[2];
    const float* wv = (const float*)d_in[3];
    const float* wo = (const float*)d_in[4];
    // d_in[5]/d_in[6] (freqs_cos/sin) unused: RoPE cancels in same-position dots.

    u16* x_bf  = (u16*)d_ws;
    u16* wqkv  = x_bf  + 16777216;
    u16* wo_bf = wqkv  + 6291456;
    u16* qkv   = wo_bf + 4194304;    // 8192 x 3072
    u16* attn  = qkv   + 25165824;   // 8192 x 2048

    conv_all<<<18432, dim3(256), 0, stream>>>(x, wq, wk, wv, wo, x_bf, wqkv, wo_bf);

    // fused QKV projection: [8192 x 2048] x [3072 x 2048]^T -> [8192 x 3072]
    // 256x192 tile -> 32x16 = 512 blocks = 2 exact machine rounds (no tail)
    gemm_bt8<3, true><<<dim3(32, 16), dim3(512), 0, stream>>>(x_bf, wqkv, qkv,
                                                              3072, 2048);

    attn_tok<<<8192, dim3(256), 0, stream>>>(qkv, attn);

    // output projection: [8192 x 2048] x [2048 x 2048]^T -> fp32 d_out
    // 256x256 tile -> 32x8 = 256 blocks = 1 exact machine round
    gemm_bt8<4, false><<<dim3(32, 8), dim3(512), 0, stream>>>(attn, wo_bf,
                                                              (float*)d_out,
                                                              2048, 2048);
}

// Round 3
// 319.165 us; speedup vs baseline: 1.1782x; 1.0304x over previous
//
#include <hip/hip_runtime.h>

typedef unsigned short u16;
typedef __bf16 bf16x8 __attribute__((ext_vector_type(8)));
typedef float f32x4 __attribute__((ext_vector_type(4)));

#define AS1 __attribute__((address_space(1)))
#define AS3 __attribute__((address_space(3)))

__device__ inline u16 f2bf(float f) {
    union { float f; unsigned u; } c; c.f = f;
    unsigned u = c.u;
    u += 0x7fffu + ((u >> 16) & 1u);   // round-to-nearest-even
    return (u16)(u >> 16);
}
__device__ inline float bf2f(u16 b) {
    union { unsigned u; float f; } c; c.u = ((unsigned)b) << 16;
    return c.f;
}

__device__ inline void async_cp16(const void* g, void* l) {
    __builtin_amdgcn_global_load_lds((const AS1 void*)g, (AS3 void*)l, 16, 0, 0);
}

// ---------------------------------------------------------------------------
// Fused input conversions in ONE launch:
//   blocks [0, 8192):      x fp32 -> bf16, 8 elems/thread (16777216 elems)
//   blocks [8192, 18432):  wq|wk|wv -> wqkv, wo -> wo_bf, 4 elems/thread
// ---------------------------------------------------------------------------
__global__ __launch_bounds__(256)
void conv_all(const float* __restrict__ x,
              const float* __restrict__ wq, const float* __restrict__ wk,
              const float* __restrict__ wv, const float* __restrict__ wo,
              u16* __restrict__ x_bf, u16* __restrict__ wqkv,
              u16* __restrict__ wo_bf) {
    int b = blockIdx.x;
    if (b < 8192) {
        int i = (b * 256 + threadIdx.x) * 8;
        float4 f0 = *(const float4*)(x + i);
        float4 f1 = *(const float4*)(x + i + 4);
        union { u16 h[8]; uint4 v; } o;
        o.h[0] = f2bf(f0.x); o.h[1] = f2bf(f0.y);
        o.h[2] = f2bf(f0.z); o.h[3] = f2bf(f0.w);
        o.h[4] = f2bf(f1.x); o.h[5] = f2bf(f1.y);
        o.h[6] = f2bf(f1.z); o.h[7] = f2bf(f1.w);
        *(uint4*)(x_bf + i) = o.v;
    } else {
        int i = ((b - 8192) * 256 + threadIdx.x) * 4;
        const float* src;
        u16* dst;
        if (i < 4194304)       { src = wq + i;           dst = wqkv + i; }
        else if (i < 5242880)  { src = wk + (i-4194304); dst = wqkv + i; }
        else if (i < 6291456)  { src = wv + (i-5242880); dst = wqkv + i; }
        else                   { src = wo + (i-6291456); dst = wo_bf + (i-6291456); }
        float4 f = *(const float4*)src;
        union { u16 h[4]; uint2 v; } o;
        o.h[0] = f2bf(f.x); o.h[1] = f2bf(f.y);
        o.h[2] = f2bf(f.z); o.h[3] = f2bf(f.w);
        *(uint2*)dst = o.v;
    }
}

// ---------------------------------------------------------------------------
// 256 x (NI*64) x (BK=64) 8-phase bf16 GEMM, C = A * B^T (row-major, K contig)
// with COUNTED per-phase lgkm waits and cross-phase operand prefetch.
// 512 threads = 8 waves (2M x 4N), per-wave output 128 x (NI*16), acc[8][NI].
// NI=3: QKV (grid 32x16 = 512 blocks = 2 exact rounds), bg double-buffered
//       (prefetched in P4 of the previous tile). NI=4: out-proj, bg read in P1.
//
// Register operand buffers: F,G = A-frag double-buffers (4 ds_read_b128 each),
// bgA/bgB = B-frags (2*NI reads). Tail waits:
//   P1: lgkm(4)  (needs F[prefetched]+bg; G in flight)   MFMA mi0-1
//   P2: lgkm(4)  (needs G; F' in flight)                 MFMA mi2-3
//   P3: lgkm(4)  (needs F'; G' in flight)                MFMA mi4-5
//   P4: lgkm(0)  (needs G')                              MFMA mi6-7
//       then vmcnt(NI+1) [tile u+1 landed], prefetch next F (and bg for NI=3)
// Stage ledger (region staged at phase-pre => readers drained at an EARLIER
// tail, with a barrier in between -- all verified strictly):
//   P1-pre: A1,A2,A3(u+1)   [A1/A3 readers drained at (u-1)P3/P4 tails;
//                            A2 readers at (u-1)P1/P2 tails]
//   P2-pre: B0,B1(u+2)      [bg(u) drained at P1 tail]
//   P3-pre: B2[,B3],A0(u+2) [A0 readers drained at P1/P2 tails]
// Loop vmcnt(NI+1) leaves exactly tile(u+2)'s B0,B1,B2[,B3],A0 in flight.
// LDS layout/swizzle identical to the proven round-2 kernel.
// Requires: M %256==0, N %(NI*64)==0, K %128==0.
// ---------------------------------------------------------------------------
template <int NI, bool BF16_OUT>
__global__ __launch_bounds__(512, 2)
void gemm_bt8(const u16* __restrict__ A, const u16* __restrict__ B,
              void* __restrict__ Cout, int N, int K) {
    constexpr int SZ = 32768 + NI * 8192;       // bytes per LDS buffer
    __shared__ __align__(16) char ldsc[2 * SZ];

    const int tid  = threadIdx.x;
    const int w    = tid >> 6;
    const int lane = tid & 63;
    const int row0 = blockIdx.x * 256;
    const int col0 = blockIdx.y * (NI * 64);
    const int wm = w >> 2, wn = w & 3;
    const int lm = lane & 15, quad = lane >> 4;

    const int NT  = K / 64;     // K-tiles
    const int NIT = K / 128;    // main-loop iterations (2 tiles each)
    const int K64 = K * 64;

    // staging: lane l covers row (8w + (l>>3)) within a 64-row unit,
    // LDS chunk position l&7 holds global chunk (l&7)^(l>>3)  (swizzle)
    const int sr  = lane >> 3;
    const int stC = ((lane & 7) ^ sr) * 8;
    const u16* pA = A + (size_t)(row0 + w * 8 + sr) * K + stC;
    const u16* pB = B + (size_t)(col0 + w * 8 + sr) * K + stC;
    const int stagoff = w * 1024;

    // fragment read bases (byte offsets); frag row&7 == lm&7 (row blocks %8==0)
    const int cx0   = (quad ^ (lm & 7)) * 16;
    const int cx1   = cx0 ^ 64;
    const int aBase = (wm * 128 + lm) * 128;
    const int bBase = 32768 + (wn * (NI * 16) + lm) * 128;

    f32x4 acc[8][NI];
#pragma unroll
    for (int i = 0; i < 8; i++)
#pragma unroll
        for (int j = 0; j < NI; j++) acc[i][j] = (f32x4){0.f, 0.f, 0.f, 0.f};

    auto stage = [&](const u16* base, int v, int unit, int regionOff) {
        int kb = (v < NT ? v : NT - 1) * 64;    // clamp: tail re-stage (dup data)
        async_cp16(base + (size_t)unit * K64 + kb,
                   ldsc + (v & 1) * SZ + regionOff + unit * 8192 + stagoff);
    };
#define ST_A(v, u) stage(pA, (v), (u), 0)
#define ST_B(v, u) stage(pB, (v), (u), 32768)

#define LDR(off) (*(const bf16x8*)(ldsc + (off)))
#define SB __builtin_amdgcn_sched_barrier(0)
#define BAR __builtin_amdgcn_s_barrier()
#define WLG(n) asm volatile("s_waitcnt lgkmcnt(" #n ")" ::: "memory")

#define RD_AF(DST, BASEOFF, MIBASE)                                           \
    _Pragma("unroll")                                                         \
    for (int j = 0; j < 2; j++) {                                             \
        DST[j][0] = LDR((BASEOFF) + aBase + ((MIBASE) + j) * 2048 + cx0);     \
        DST[j][1] = LDR((BASEOFF) + aBase + ((MIBASE) + j) * 2048 + cx1);     \
    }
#define RD_BG(DST, BASEOFF)                                                   \
    _Pragma("unroll")                                                         \
    for (int ni = 0; ni < NI; ni++) {                                         \
        DST[ni][0] = LDR((BASEOFF) + bBase + ni * 2048 + cx0);                \
        DST[ni][1] = LDR((BASEOFF) + bBase + ni * 2048 + cx1);                \
    }
#define MFMA_TAIL(MI0, AF, BG)                                                \
    __builtin_amdgcn_s_setprio(1);                                            \
    _Pragma("unroll")                                                         \
    for (int s = 0; s < 2; s++)                                               \
        _Pragma("unroll")                                                     \
        for (int j = 0; j < 2; j++)                                           \
            _Pragma("unroll")                                                 \
            for (int ni = 0; ni < NI; ni++)                                   \
                acc[(MI0) + j][ni] = __builtin_amdgcn_mfma_f32_16x16x32_bf16( \
                    AF[j][s], BG[ni][s], acc[(MI0) + j][ni], 0, 0, 0);        \
    __builtin_amdgcn_s_setprio(0);

    bf16x8 bgA[NI][2], bgB[NI][2], F[2][2], G[2][2];

    // prologue: t0 complete (4+NI units) + t1 {B*, A0} (NI+1 units)
#pragma unroll
    for (int u = 0; u < 4; u++) ST_A(0, u);
#pragma unroll
    for (int u = 0; u < NI; u++) ST_B(0, u);
#pragma unroll
    for (int u = 0; u < NI; u++) ST_B(1, u);
    ST_A(1, 0);
    if constexpr (NI == 3) asm volatile("s_waitcnt vmcnt(4)" ::: "memory");
    else                   asm volatile("s_waitcnt vmcnt(5)" ::: "memory");
    SB;
    if constexpr (NI == 3) { RD_BG(bgA, 0) }
    RD_AF(F, 0, 0)
    SB;
    BAR;

#define HALF_ITER(u, BO, BN, BGC, BGN)                                        \
    {                                                                         \
        /* P1 */                                                              \
        if constexpr (NI == 4) { RD_BG(BGC, BO) }                             \
        SB;                                                                   \
        RD_AF(G, BO, 2)                                                       \
        SB;                                                                   \
        ST_A((u) + 1, 1); ST_A((u) + 1, 2); ST_A((u) + 1, 3);                 \
        SB;                                                                   \
        BAR;                                                                  \
        WLG(4);                                                               \
        SB;                                                                   \
        MFMA_TAIL(0, F, BGC)                                                  \
        SB;                                                                   \
        BAR;                                                                  \
        /* P2 */                                                              \
        RD_AF(F, BO, 4)                                                       \
        SB;                                                                   \
        ST_B((u) + 2, 0); ST_B((u) + 2, 1);                                   \
        SB;                                                                   \
        BAR;                                                                  \
        WLG(4);                                                               \
        SB;                                                                   \
        MFMA_TAIL(2, G, BGC)                                                  \
        SB;                                                                   \
        BAR;                                                                  \
        /* P3 */                                                              \
        RD_AF(G, BO, 6)                                                       \
        SB;                                                                   \
        ST_B((u) + 2, 2);                                                     \
        if constexpr (NI == 4) { ST_B((u) + 2, 3); }                          \
        ST_A((u) + 2, 0);                                                     \
        SB;                                                                   \
        BAR;                                                                  \
        WLG(4);                                                               \
        SB;                                                                   \
        MFMA_TAIL(4, F, BGC)                                                  \
        SB;                                                                   \
        BAR;                                                                  \
        /* P4 (no pre-stages; single barrier at end) */                       \
        WLG(0);                                                               \
        SB;                                                                   \
        MFMA_TAIL(6, G, BGC)                                                  \
        SB;                                                                   \
        if constexpr (NI == 3) asm volatile("s_waitcnt vmcnt(4)" ::: "memory");\
        else                   asm volatile("s_waitcnt vmcnt(5)" ::: "memory");\
        SB;                                                                   \
        if constexpr (NI == 3) { RD_BG(BGN, BN) }                             \
        RD_AF(F, BN, 0)                                                       \
        SB;                                                                   \
        BAR;                                                                  \
    }

    for (int it = 0; it < NIT; ++it) {
        const int t = 2 * it;
        HALF_ITER(t, 0, SZ, bgA, bgB)
        HALF_ITER(t + 1, SZ, 0, bgB, bgA)
    }

#undef HALF_ITER
#undef MFMA_TAIL
#undef RD_BG
#undef RD_AF
#undef WLG
#undef BAR
#undef SB
#undef LDR
#undef ST_A
#undef ST_B

    // epilogue: C/D layout col = lane&15, row = quad*4 + reg
    const int rbase = row0 + wm * 128 + quad * 4;
    const int cbase = col0 + wn * (NI * 16) + lm;
    if (BF16_OUT) {
        u16* C = (u16*)Cout;
#pragma unroll
        for (int mi = 0; mi < 8; mi++)
#pragma unroll
            for (int r = 0; r < 4; r++) {
                size_t ro = (size_t)(rbase + mi * 16 + r) * N;
#pragma unroll
                for (int ni = 0; ni < NI; ni++)
                    C[ro + cbase + ni * 16] = f2bf(acc[mi][ni][r]);
            }
    } else {
        float* C = (float*)Cout;
#pragma unroll
        for (int mi = 0; mi < 8; mi++)
#pragma unroll
            for (int r = 0; r < 4; r++) {
                size_t ro = (size_t)(rbase + mi * 16 + r) * N;
#pragma unroll
                for (int ni = 0; ni < NI; ni++)
                    C[ro + cbase + ni * 16] = acc[mi][ni][r];
            }
    }
}

// ---------------------------------------------------------------------------
// Per-token attention. qkv row: [q(2048) | k(512) | v(512)] bf16.
// RoPE dropped (same-position q/k rotation cancels in the dot);
// 4x head repeat collapsed (softmax over 8 distinct kv-heads).
// ---------------------------------------------------------------------------
__global__ __launch_bounds__(256)
void attn_tok(const u16* __restrict__ qkv, u16* __restrict__ out) {
    __shared__ float kvf[1024];   // k (512 floats) then v (512 floats)
    const int tok = blockIdx.x;
    const int t = threadIdx.x;
    const u16* qrow = qkv + (size_t)tok * 3072;

    {   // stage k|v (contiguous 1024 bf16) into LDS as fp32
        uint2 w = *(const uint2*)(qrow + 2048 + t * 4);
        kvf[t * 4 + 0] = bf2f((u16)(w.x & 0xffff));
        kvf[t * 4 + 1] = bf2f((u16)(w.x >> 16));
        kvf[t * 4 + 2] = bf2f((u16)(w.y & 0xffff));
        kvf[t * 4 + 3] = bf2f((u16)(w.y >> 16));
    }
    __syncthreads();

    const int h = t >> 3, j = t & 7;
    float qf[8];
    {
        uint4 w = *(const uint4*)(qrow + h * 64 + j * 8);
        unsigned ws4[4] = {w.x, w.y, w.z, w.w};
#pragma unroll
        for (int i = 0; i < 4; i++) {
            qf[2 * i]     = bf2f((u16)(ws4[i] & 0xffff));
            qf[2 * i + 1] = bf2f((u16)(ws4[i] >> 16));
        }
    }

    float s[8];
#pragma unroll
    for (int g = 0; g < 8; g++) {
        const float* kk = kvf + g * 64 + j * 8;
        float a = 0.f;
#pragma unroll
        for (int d = 0; d < 8; d++) a += qf[d] * kk[d];
        s[g] = a;
    }
#pragma unroll
    for (int g = 0; g < 8; g++) {   // reduce across the head's 8 lanes
        s[g] += __shfl_xor(s[g], 1);
        s[g] += __shfl_xor(s[g], 2);
        s[g] += __shfl_xor(s[g], 4);
    }
    float m = -1e30f;
#pragma unroll
    for (int g = 0; g < 8; g++) { s[g] *= 0.125f; m = fmaxf(m, s[g]); }
    float p[8], l = 0.f;
#pragma unroll
    for (int g = 0; g < 8; g++) { p[g] = __expf(s[g] - m); l += p[g]; }
    float rl = 1.f / l;

    float o[8] = {0, 0, 0, 0, 0, 0, 0, 0};
#pragma unroll
    for (int g = 0; g < 8; g++) {
        float w = p[g] * rl;
        const float* vv = kvf + 512 + g * 64 + j * 8;
#pragma unroll
        for (int d = 0; d < 8; d++) o[d] += w * vv[d];
    }

    unsigned po[4];
#pragma unroll
    for (int i = 0; i < 4; i++)
        po[i] = (unsigned)f2bf(o[2 * i]) | ((unsigned)f2bf(o[2 * i + 1]) << 16);
    uint4 wo_; wo_.x = po[0]; wo_.y = po[1]; wo_.z = po[2]; wo_.w = po[3];
    *(uint4*)(out + (size_t)tok * 2048 + h * 64 + j * 8) = wo_;
}

// ---------------------------------------------------------------------------
// B=4, S=2048, DIM=2048, H=32, KVH=8, HD=64. Tokens M = 8192.
// Workspace (u16 elems): x_bf/attn (aliased) 16777216 | wqkv 6291456
//                        | wo_bf 4194304 | qkv 25165824   (104.9 MB)
// attn reuses x_bf: x_bf dead after the QKV GEMM; attn written after it.
// ---------------------------------------------------------------------------
extern "C" void kernel_launch(void* const* d_in, const int* in_sizes, int n_in,
                              void* d_out, int out_size, void* d_ws, size_t ws_size,
                              hipStream_t stream) {
    const float* x  = (const float*)d_in[0];
    const float* wq = (const float*)d_in[1];
    const float* wk = (const float*)d_in[2];
    const float* wv = (const float*)d_in[3];
    const float* wo = (const float*)d_in[4];
    // d_in[5]/d_in[6] (freqs_cos/sin) unused: RoPE cancels in same-position dots.

    u16* x_bf  = (u16*)d_ws;
    u16* wqkv  = x_bf  + 16777216;
    u16* wo_bf = wqkv  + 6291456;
    u16* qkv   = wo_bf + 4194304;    // 8192 x 3072
    u16* attn  = x_bf;               // alias: x_bf dead after QKV GEMM

    conv_all<<<18432, dim3(256), 0, stream>>>(x, wq, wk, wv, wo, x_bf, wqkv, wo_bf);

    // fused QKV projection: [8192 x 2048] x [3072 x 2048]^T -> [8192 x 3072]
    // 256x192 tile -> 32x16 = 512 blocks = 2 exact machine rounds
    gemm_bt8<3, true><<<dim3(32, 16), dim3(512), 0, stream>>>(x_bf, wqkv, qkv,
                                                              3072, 2048);

    attn_tok<<<8192, dim3(256), 0, stream>>>(qkv, attn);

    // output projection: [8192 x 2048] x [2048 x 2048]^T -> fp32 d_out
    // 256x256 tile -> 32x8 = 256 blocks = 1 exact machine round
    gemm_bt8<4, false><<<dim3(32, 8), dim3(512), 0, stream>>>(attn, wo_bf,
                                                              (float*)d_out,
                                                              2048, 2048);
}